// Round 1
// baseline (408.158 us; speedup 1.0000x reference)
//
#include <hip/hip_runtime.h>

constexpr int D = 128;

// ---------------- CSR build ----------------

__global__ void k_init_cnt(int* __restrict__ cnt, int n) {
    int i = blockIdx.x * 256 + threadIdx.x;
    if (i < n) cnt[i] = 0;
}

__global__ void k_count(const int* __restrict__ dst, int* __restrict__ cnt, int E) {
    int e = blockIdx.x * 256 + threadIdx.x;
    if (e < E) atomicAdd(&cnt[dst[e]], 1);
}

__global__ void k_dinv(const int* __restrict__ cnt, float* __restrict__ dinv, int n) {
    int i = blockIdx.x * 256 + threadIdx.x;
    if (i < n) dinv[i] = rsqrtf((float)(cnt[i] + 1));  // +1 self-loop
}

__global__ __launch_bounds__(1024) void k_scan(const int* __restrict__ cnt,
                                               int* __restrict__ rowptr,
                                               int* __restrict__ cursor, int n) {
    __shared__ int sm[1024];
    __shared__ int soff;
    int tid = threadIdx.x;
    if (tid == 0) soff = 0;
    __syncthreads();
    for (int base = 0; base < n; base += 1024) {
        int idx = base + tid;
        int v = (idx < n) ? cnt[idx] : 0;
        sm[tid] = v;
        __syncthreads();
        for (int off = 1; off < 1024; off <<= 1) {
            int t = (tid >= off) ? sm[tid - off] : 0;
            __syncthreads();
            sm[tid] += t;
            __syncthreads();
        }
        int excl = sm[tid] - v;
        int total = sm[1023];
        if (idx < n) {
            int rp = soff + excl;
            rowptr[idx] = rp;
            cursor[idx] = rp;
        }
        __syncthreads();
        if (tid == 0) soff += total;
        __syncthreads();
    }
    if (tid == 0) rowptr[n] = soff;
}

__global__ void k_fill(const int* __restrict__ src, const int* __restrict__ dst,
                       const float* __restrict__ dinv, int* __restrict__ cursor,
                       int2* __restrict__ csr, int E) {
    int e = blockIdx.x * 256 + threadIdx.x;
    if (e < E) {
        int s = src[e], d = dst[e];
        int p = atomicAdd(&cursor[d], 1);
        float w = dinv[s] * dinv[d];
        csr[p] = make_int2(s, __float_as_int(w));
    }
}

// ---------------- W' = W2 @ M1 ; c' = b2 @ M1 + c1 ----------------

__global__ void k_wprime(const float* __restrict__ W2, const float* __restrict__ M1,
                         const float* __restrict__ b2, const float* __restrict__ c1,
                         float* __restrict__ Wp, float* __restrict__ cp) {
    int b = blockIdx.x, t = threadIdx.x;
    if (b < 64) {
        int idx = b * 256 + t;
        int i = idx >> 7, j = idx & 127;
        float acc = 0.f;
        for (int k = 0; k < 128; ++k) acc = fmaf(W2[i * 128 + k], M1[k * 128 + j], acc);
        Wp[idx] = acc;
    } else if (t < 128) {
        float acc = c1[t];
        for (int k = 0; k < 128; ++k) acc = fmaf(b2[k], M1[k * 128 + t], acc);
        cp[t] = acc;
    }
}

// ---------------- aggregation: out = S . A  (symmetric-normalized, self-loops) ----------------

__global__ __launch_bounds__(256) void k_agg(const float* __restrict__ A,
                                             const int* __restrict__ rowptr,
                                             const int2* __restrict__ csr,
                                             const float* __restrict__ dinv,
                                             float* __restrict__ out, int n) {
    int wave = threadIdx.x >> 6;
    int lane = threadIdx.x & 63;
    int i = blockIdx.x * 4 + wave;
    if (i >= n) return;
    const float2* __restrict__ A2 = reinterpret_cast<const float2*>(A);
    float ws = dinv[i];
    ws = ws * ws;
    float2 a = A2[i * 64 + lane];
    float accx = ws * a.x, accy = ws * a.y;
    int beg = rowptr[i], end = rowptr[i + 1];
    int e = beg;
    for (; e + 2 <= end; e += 2) {
        int2 p0 = csr[e];
        int2 p1 = csr[e + 1];
        float2 v0 = A2[p0.x * 64 + lane];
        float2 v1 = A2[p1.x * 64 + lane];
        float w0 = __int_as_float(p0.y);
        float w1 = __int_as_float(p1.y);
        accx = fmaf(w0, v0.x, accx);
        accy = fmaf(w0, v0.y, accy);
        accx = fmaf(w1, v1.x, accx);
        accy = fmaf(w1, v1.y, accy);
    }
    if (e < end) {
        int2 p0 = csr[e];
        float2 v0 = A2[p0.x * 64 + lane];
        float w0 = __int_as_float(p0.y);
        accx = fmaf(w0, v0.x, accx);
        accy = fmaf(w0, v0.y, accy);
    }
    float2 o;
    o.x = accx;
    o.y = accy;
    reinterpret_cast<float2*>(out)[i * 64 + lane] = o;
}

// ---------------- GEMM: out = epilogue(A @ W + bias) ----------------
// MODE 0: out[N,128] = relu(A@W + bias)
// MODE 1: out[N,1]   = relu(A@W + bias) . m2 + m2b[0]

template <int MODE>
__global__ __launch_bounds__(256) void k_gemm(const float* __restrict__ A,
                                              const float* __restrict__ W,
                                              const float* __restrict__ bias,
                                              const float* __restrict__ m2,
                                              const float* __restrict__ m2b,
                                              float* __restrict__ out, int n) {
    __shared__ float Ht[16 * 64];    // k-major: Ht[k][row]
    __shared__ float Wt[16 * 128];   // Wt[k][col]
    int tid = threadIdx.x;
    int rg = tid >> 4;   // 0..15 -> rows rg*4 .. rg*4+3
    int cg = tid & 15;   // 0..15 -> cols cg*8 .. cg*8+7
    int r0 = blockIdx.x * 64;

    float acc[4][8];
#pragma unroll
    for (int ri = 0; ri < 4; ++ri)
#pragma unroll
        for (int ci = 0; ci < 8; ++ci) acc[ri][ci] = 0.f;

    for (int k0 = 0; k0 < 128; k0 += 16) {
        // stage A tile (64 rows x 16 k), transposed into Ht[k][row]
        {
            int row = tid >> 2;  // 0..63
            int kq = tid & 3;    // 0..3
            int grow = r0 + row;
            if (grow > n - 1) grow = n - 1;
            float4 v = *reinterpret_cast<const float4*>(&A[grow * 128 + k0 + kq * 4]);
            Ht[(kq * 4 + 0) * 64 + row] = v.x;
            Ht[(kq * 4 + 1) * 64 + row] = v.y;
            Ht[(kq * 4 + 2) * 64 + row] = v.z;
            Ht[(kq * 4 + 3) * 64 + row] = v.w;
        }
        // stage W tile (16 k x 128 cols)
        for (int q = tid; q < 512; q += 256) {
            int kk = q >> 5;
            int cc = (q & 31) * 4;
            *reinterpret_cast<float4*>(&Wt[kk * 128 + cc]) =
                *reinterpret_cast<const float4*>(&W[(k0 + kk) * 128 + cc]);
        }
        __syncthreads();
#pragma unroll
        for (int k = 0; k < 16; ++k) {
            float4 a = *reinterpret_cast<float4*>(&Ht[k * 64 + rg * 4]);
            float4 b0 = *reinterpret_cast<float4*>(&Wt[k * 128 + cg * 8]);
            float4 b1 = *reinterpret_cast<float4*>(&Wt[k * 128 + cg * 8 + 4]);
            float av[4] = {a.x, a.y, a.z, a.w};
            float bv[8] = {b0.x, b0.y, b0.z, b0.w, b1.x, b1.y, b1.z, b1.w};
#pragma unroll
            for (int ri = 0; ri < 4; ++ri)
#pragma unroll
                for (int ci = 0; ci < 8; ++ci)
                    acc[ri][ci] = fmaf(av[ri], bv[ci], acc[ri][ci]);
        }
        __syncthreads();
    }

    if (MODE == 0) {
        float4 bb0 = *reinterpret_cast<const float4*>(&bias[cg * 8]);
        float4 bb1 = *reinterpret_cast<const float4*>(&bias[cg * 8 + 4]);
        float bv[8] = {bb0.x, bb0.y, bb0.z, bb0.w, bb1.x, bb1.y, bb1.z, bb1.w};
#pragma unroll
        for (int ri = 0; ri < 4; ++ri) {
            int r = r0 + rg * 4 + ri;
            if (r < n) {
                float4 o0, o1;
                o0.x = fmaxf(acc[ri][0] + bv[0], 0.f);
                o0.y = fmaxf(acc[ri][1] + bv[1], 0.f);
                o0.z = fmaxf(acc[ri][2] + bv[2], 0.f);
                o0.w = fmaxf(acc[ri][3] + bv[3], 0.f);
                o1.x = fmaxf(acc[ri][4] + bv[4], 0.f);
                o1.y = fmaxf(acc[ri][5] + bv[5], 0.f);
                o1.z = fmaxf(acc[ri][6] + bv[6], 0.f);
                o1.w = fmaxf(acc[ri][7] + bv[7], 0.f);
                *reinterpret_cast<float4*>(&out[r * 128 + cg * 8]) = o0;
                *reinterpret_cast<float4*>(&out[r * 128 + cg * 8 + 4]) = o1;
            }
        }
    } else {
        float4 bb0 = *reinterpret_cast<const float4*>(&bias[cg * 8]);
        float4 bb1 = *reinterpret_cast<const float4*>(&bias[cg * 8 + 4]);
        float bv[8] = {bb0.x, bb0.y, bb0.z, bb0.w, bb1.x, bb1.y, bb1.z, bb1.w};
        float4 mm0 = *reinterpret_cast<const float4*>(&m2[cg * 8]);
        float4 mm1 = *reinterpret_cast<const float4*>(&m2[cg * 8 + 4]);
        float mv[8] = {mm0.x, mm0.y, mm0.z, mm0.w, mm1.x, mm1.y, mm1.z, mm1.w};
        float m2bv = m2b[0];
#pragma unroll
        for (int ri = 0; ri < 4; ++ri) {
            float p = 0.f;
#pragma unroll
            for (int ci = 0; ci < 8; ++ci) {
                float v = fmaxf(acc[ri][ci] + bv[ci], 0.f);
                p = fmaf(v, mv[ci], p);
            }
            p += __shfl_xor(p, 1);
            p += __shfl_xor(p, 2);
            p += __shfl_xor(p, 4);
            p += __shfl_xor(p, 8);
            int r = r0 + rg * 4 + ri;
            if (cg == 0 && r < n) out[r] = p + m2bv;
        }
    }
}

// ---------------- launch ----------------

extern "C" void kernel_launch(void* const* d_in, const int* in_sizes, int n_in,
                              void* d_out, int out_size, void* d_ws, size_t ws_size,
                              hipStream_t stream) {
    const float* x = (const float*)d_in[0];
    const int* ei = (const int*)d_in[1];
    const float* W0 = (const float*)d_in[2];
    const float* b0 = (const float*)d_in[3];
    const float* W1 = (const float*)d_in[4];
    const float* b1 = (const float*)d_in[5];
    const float* W2 = (const float*)d_in[6];
    const float* b2 = (const float*)d_in[7];
    const float* M1 = (const float*)d_in[8];
    const float* c1 = (const float*)d_in[9];
    const float* m2 = (const float*)d_in[10];
    const float* m2b = (const float*)d_in[11];
    float* out = (float*)d_out;

    int N = in_sizes[0] / D;
    int E = in_sizes[1] / 2;
    const int* src = ei;
    const int* dst = ei + E;

    char* ws = (char*)d_ws;
    size_t off = 0;
    auto alloc = [&](size_t bytes) -> void* {
        void* p = ws + off;
        off += (bytes + 255) & ~(size_t)255;
        return p;
    };

    float* bufA = (float*)alloc((size_t)N * D * 4);
    float* bufB = (float*)alloc((size_t)N * D * 4);
    int* cnt = (int*)alloc((size_t)N * 4);
    float* dinv = (float*)alloc((size_t)N * 4);
    int* rowptr = (int*)alloc((size_t)(N + 1) * 4);
    int* cursor = (int*)alloc((size_t)N * 4);
    int2* csr = (int2*)alloc((size_t)E * 8);
    float* Wp = (float*)alloc((size_t)D * D * 4);
    float* cp = (float*)alloc((size_t)D * 4);

    int gN = (N + 255) / 256;
    int gE = (E + 255) / 256;
    int gAgg = (N + 3) / 4;
    int gGemm = (N + 63) / 64;

    k_init_cnt<<<gN, 256, 0, stream>>>(cnt, N);
    k_count<<<gE, 256, 0, stream>>>(dst, cnt, E);
    k_dinv<<<gN, 256, 0, stream>>>(cnt, dinv, N);
    k_scan<<<1, 1024, 0, stream>>>(cnt, rowptr, cursor, N);
    k_fill<<<gE, 256, 0, stream>>>(src, dst, dinv, cursor, csr, E);
    k_wprime<<<65, 256, 0, stream>>>(W2, M1, b2, c1, Wp, cp);

    // layer 0: t = S.x ; h0 = relu(t@W0+b0)
    k_agg<<<gAgg, 256, 0, stream>>>(x, rowptr, csr, dinv, bufA, N);
    k_gemm<0><<<gGemm, 256, 0, stream>>>(bufA, W0, b0, nullptr, nullptr, bufB, N);
    // layer 1
    k_agg<<<gAgg, 256, 0, stream>>>(bufB, rowptr, csr, dinv, bufA, N);
    k_gemm<0><<<gGemm, 256, 0, stream>>>(bufA, W1, b1, nullptr, nullptr, bufB, N);
    // layer 2 + fused MLP head
    k_agg<<<gAgg, 256, 0, stream>>>(bufB, rowptr, csr, dinv, bufA, N);
    k_gemm<1><<<gGemm, 256, 0, stream>>>(bufA, Wp, cp, m2, m2b, out, N);
}

// Round 2
// 326.953 us; speedup vs baseline: 1.2484x; 1.2484x over previous
//
#include <hip/hip_runtime.h>

constexpr int D = 128;

// ---------------- CSR build ----------------

__global__ void k_init_cnt(int* __restrict__ cnt, int n) {
    int i = blockIdx.x * 256 + threadIdx.x;
    if (i < n) cnt[i] = 0;
}

__global__ void k_count(const int* __restrict__ dst, int* __restrict__ cnt, int E) {
    int e = blockIdx.x * 256 + threadIdx.x;
    if (e < E) atomicAdd(&cnt[dst[e]], 1);
}

__global__ void k_dinv(const int* __restrict__ cnt, float* __restrict__ dinv, int n) {
    int i = blockIdx.x * 256 + threadIdx.x;
    if (i < n) dinv[i] = rsqrtf((float)(cnt[i] + 1));  // +1 self-loop
}

// --- 3-phase scan: per-block sum -> scan sums -> local scan + offset ---

__global__ __launch_bounds__(256) void k_blocksum(const int* __restrict__ cnt,
                                                  int* __restrict__ bsum, int n) {
    __shared__ int sm[256];
    int tid = threadIdx.x;
    int i = blockIdx.x * 256 + tid;
    sm[tid] = (i < n) ? cnt[i] : 0;
    __syncthreads();
    for (int off = 128; off > 0; off >>= 1) {
        if (tid < off) sm[tid] += sm[tid + off];
        __syncthreads();
    }
    if (tid == 0) bsum[blockIdx.x] = sm[0];
}

__global__ __launch_bounds__(1024) void k_scan_bsums(int* __restrict__ bsum, int nb,
                                                     int* __restrict__ rowptr, int n) {
    __shared__ int sm[1024];
    int tid = threadIdx.x;
    int v = (tid < nb) ? bsum[tid] : 0;
    sm[tid] = v;
    __syncthreads();
    for (int off = 1; off < 1024; off <<= 1) {
        int t = (tid >= off) ? sm[tid - off] : 0;
        __syncthreads();
        sm[tid] += t;
        __syncthreads();
    }
    if (tid < nb) bsum[tid] = sm[tid] - v;  // exclusive
    if (tid == 1023) rowptr[n] = sm[1023];
}

__global__ __launch_bounds__(256) void k_local_scan(const int* __restrict__ cnt,
                                                    const int* __restrict__ bsum,
                                                    int* __restrict__ rowptr,
                                                    int* __restrict__ cursor, int n) {
    __shared__ int sm[256];
    int tid = threadIdx.x;
    int i = blockIdx.x * 256 + tid;
    int v = (i < n) ? cnt[i] : 0;
    sm[tid] = v;
    __syncthreads();
    for (int off = 1; off < 256; off <<= 1) {
        int t = (tid >= off) ? sm[tid - off] : 0;
        __syncthreads();
        sm[tid] += t;
        __syncthreads();
    }
    if (i < n) {
        int rp = bsum[blockIdx.x] + sm[tid] - v;
        rowptr[i] = rp;
        cursor[i] = rp;
    }
}

__global__ void k_fill(const int* __restrict__ src, const int* __restrict__ dst,
                       const float* __restrict__ dinv, int* __restrict__ cursor,
                       int2* __restrict__ csr, int E) {
    int e = blockIdx.x * 256 + threadIdx.x;
    if (e < E) {
        int s = src[e], d = dst[e];
        int p = atomicAdd(&cursor[d], 1);
        float w = dinv[s] * dinv[d];
        csr[p] = make_int2(s, __float_as_int(w));
    }
}

// ---------------- W' = W2 @ M1 ; c' = b2 @ M1 + c1 ----------------

__global__ void k_wprime(const float* __restrict__ W2, const float* __restrict__ M1,
                         const float* __restrict__ b2, const float* __restrict__ c1,
                         float* __restrict__ Wp, float* __restrict__ cp) {
    int b = blockIdx.x, t = threadIdx.x;
    if (b < 64) {
        int idx = b * 256 + t;
        int i = idx >> 7, j = idx & 127;
        float acc = 0.f;
        for (int k = 0; k < 128; ++k) acc = fmaf(W2[i * 128 + k], M1[k * 128 + j], acc);
        Wp[idx] = acc;
    } else if (t < 128) {
        float acc = c1[t];
        for (int k = 0; k < 128; ++k) acc = fmaf(b2[k], M1[k * 128 + t], acc);
        cp[t] = acc;
    }
}

// ---------------- aggregation: out = S . A  (symmetric-normalized, self-loops) ----------------

__global__ __launch_bounds__(256) void k_agg(const float* __restrict__ A,
                                             const int* __restrict__ rowptr,
                                             const int2* __restrict__ csr,
                                             const float* __restrict__ dinv,
                                             float* __restrict__ out, int n) {
    int wave = threadIdx.x >> 6;
    int lane = threadIdx.x & 63;
    int i = blockIdx.x * 4 + wave;
    if (i >= n) return;
    const float2* __restrict__ A2 = reinterpret_cast<const float2*>(A);
    float ws = dinv[i];
    ws = ws * ws;
    float2 a = A2[i * 64 + lane];
    float accx = ws * a.x, accy = ws * a.y;
    int beg = rowptr[i], end = rowptr[i + 1];
    int e = beg;
    for (; e + 2 <= end; e += 2) {
        int2 p0 = csr[e];
        int2 p1 = csr[e + 1];
        float2 v0 = A2[p0.x * 64 + lane];
        float2 v1 = A2[p1.x * 64 + lane];
        float w0 = __int_as_float(p0.y);
        float w1 = __int_as_float(p1.y);
        accx = fmaf(w0, v0.x, accx);
        accy = fmaf(w0, v0.y, accy);
        accx = fmaf(w1, v1.x, accx);
        accy = fmaf(w1, v1.y, accy);
    }
    if (e < end) {
        int2 p0 = csr[e];
        float2 v0 = A2[p0.x * 64 + lane];
        float w0 = __int_as_float(p0.y);
        accx = fmaf(w0, v0.x, accx);
        accy = fmaf(w0, v0.y, accy);
    }
    float2 o;
    o.x = accx;
    o.y = accy;
    reinterpret_cast<float2*>(out)[i * 64 + lane] = o;
}

// ---------------- GEMM: out = epilogue(A @ W + bias) ----------------
// MODE 0: out[N,128] = relu(A@W + bias)
// MODE 1: out[N,1]   = relu(A@W + bias) . m2 + m2b[0]

template <int MODE>
__global__ __launch_bounds__(256) void k_gemm(const float* __restrict__ A,
                                              const float* __restrict__ W,
                                              const float* __restrict__ bias,
                                              const float* __restrict__ m2,
                                              const float* __restrict__ m2b,
                                              float* __restrict__ out, int n) {
    __shared__ float Ht[16 * 64];    // k-major: Ht[k][row]
    __shared__ float Wt[16 * 128];   // Wt[k][col]
    int tid = threadIdx.x;
    int rg = tid >> 4;   // 0..15 -> rows rg*4 .. rg*4+3
    int cg = tid & 15;   // 0..15 -> cols cg*8 .. cg*8+7
    int r0 = blockIdx.x * 64;

    float acc[4][8];
#pragma unroll
    for (int ri = 0; ri < 4; ++ri)
#pragma unroll
        for (int ci = 0; ci < 8; ++ci) acc[ri][ci] = 0.f;

    for (int k0 = 0; k0 < 128; k0 += 16) {
        // stage A tile (64 rows x 16 k), transposed into Ht[k][row]
        {
            int row = tid >> 2;  // 0..63
            int kq = tid & 3;    // 0..3
            int grow = r0 + row;
            if (grow > n - 1) grow = n - 1;
            float4 v = *reinterpret_cast<const float4*>(&A[grow * 128 + k0 + kq * 4]);
            Ht[(kq * 4 + 0) * 64 + row] = v.x;
            Ht[(kq * 4 + 1) * 64 + row] = v.y;
            Ht[(kq * 4 + 2) * 64 + row] = v.z;
            Ht[(kq * 4 + 3) * 64 + row] = v.w;
        }
        // stage W tile (16 k x 128 cols)
        for (int q = tid; q < 512; q += 256) {
            int kk = q >> 5;
            int cc = (q & 31) * 4;
            *reinterpret_cast<float4*>(&Wt[kk * 128 + cc]) =
                *reinterpret_cast<const float4*>(&W[(k0 + kk) * 128 + cc]);
        }
        __syncthreads();
#pragma unroll
        for (int k = 0; k < 16; ++k) {
            float4 a = *reinterpret_cast<float4*>(&Ht[k * 64 + rg * 4]);
            float4 b0 = *reinterpret_cast<float4*>(&Wt[k * 128 + cg * 8]);
            float4 b1 = *reinterpret_cast<float4*>(&Wt[k * 128 + cg * 8 + 4]);
            float av[4] = {a.x, a.y, a.z, a.w};
            float bv[8] = {b0.x, b0.y, b0.z, b0.w, b1.x, b1.y, b1.z, b1.w};
#pragma unroll
            for (int ri = 0; ri < 4; ++ri)
#pragma unroll
                for (int ci = 0; ci < 8; ++ci)
                    acc[ri][ci] = fmaf(av[ri], bv[ci], acc[ri][ci]);
        }
        __syncthreads();
    }

    if (MODE == 0) {
        float4 bb0 = *reinterpret_cast<const float4*>(&bias[cg * 8]);
        float4 bb1 = *reinterpret_cast<const float4*>(&bias[cg * 8 + 4]);
        float bv[8] = {bb0.x, bb0.y, bb0.z, bb0.w, bb1.x, bb1.y, bb1.z, bb1.w};
#pragma unroll
        for (int ri = 0; ri < 4; ++ri) {
            int r = r0 + rg * 4 + ri;
            if (r < n) {
                float4 o0, o1;
                o0.x = fmaxf(acc[ri][0] + bv[0], 0.f);
                o0.y = fmaxf(acc[ri][1] + bv[1], 0.f);
                o0.z = fmaxf(acc[ri][2] + bv[2], 0.f);
                o0.w = fmaxf(acc[ri][3] + bv[3], 0.f);
                o1.x = fmaxf(acc[ri][4] + bv[4], 0.f);
                o1.y = fmaxf(acc[ri][5] + bv[5], 0.f);
                o1.z = fmaxf(acc[ri][6] + bv[6], 0.f);
                o1.w = fmaxf(acc[ri][7] + bv[7], 0.f);
                *reinterpret_cast<float4*>(&out[r * 128 + cg * 8]) = o0;
                *reinterpret_cast<float4*>(&out[r * 128 + cg * 8 + 4]) = o1;
            }
        }
    } else {
        float4 bb0 = *reinterpret_cast<const float4*>(&bias[cg * 8]);
        float4 bb1 = *reinterpret_cast<const float4*>(&bias[cg * 8 + 4]);
        float bv[8] = {bb0.x, bb0.y, bb0.z, bb0.w, bb1.x, bb1.y, bb1.z, bb1.w};
        float4 mm0 = *reinterpret_cast<const float4*>(&m2[cg * 8]);
        float4 mm1 = *reinterpret_cast<const float4*>(&m2[cg * 8 + 4]);
        float mv[8] = {mm0.x, mm0.y, mm0.z, mm0.w, mm1.x, mm1.y, mm1.z, mm1.w};
        float m2bv = m2b[0];
#pragma unroll
        for (int ri = 0; ri < 4; ++ri) {
            float p = 0.f;
#pragma unroll
            for (int ci = 0; ci < 8; ++ci) {
                float v = fmaxf(acc[ri][ci] + bv[ci], 0.f);
                p = fmaf(v, mv[ci], p);
            }
            p += __shfl_xor(p, 1);
            p += __shfl_xor(p, 2);
            p += __shfl_xor(p, 4);
            p += __shfl_xor(p, 8);
            int r = r0 + rg * 4 + ri;
            if (cg == 0 && r < n) out[r] = p + m2bv;
        }
    }
}

// ---------------- launch ----------------

extern "C" void kernel_launch(void* const* d_in, const int* in_sizes, int n_in,
                              void* d_out, int out_size, void* d_ws, size_t ws_size,
                              hipStream_t stream) {
    const float* x = (const float*)d_in[0];
    const int* ei = (const int*)d_in[1];
    const float* W0 = (const float*)d_in[2];
    const float* b0 = (const float*)d_in[3];
    const float* W1 = (const float*)d_in[4];
    const float* b1 = (const float*)d_in[5];
    const float* W2 = (const float*)d_in[6];
    const float* b2 = (const float*)d_in[7];
    const float* M1 = (const float*)d_in[8];
    const float* c1 = (const float*)d_in[9];
    const float* m2 = (const float*)d_in[10];
    const float* m2b = (const float*)d_in[11];
    float* out = (float*)d_out;

    int N = in_sizes[0] / D;
    int E = in_sizes[1] / 2;
    const int* src = ei;
    const int* dst = ei + E;

    char* ws = (char*)d_ws;
    size_t off = 0;
    auto alloc = [&](size_t bytes) -> void* {
        void* p = ws + off;
        off += (bytes + 255) & ~(size_t)255;
        return p;
    };

    int gN = (N + 255) / 256;
    int gE = (E + 255) / 256;
    int gAgg = (N + 3) / 4;
    int gGemm = (N + 63) / 64;

    float* bufA = (float*)alloc((size_t)N * D * 4);
    float* bufB = (float*)alloc((size_t)N * D * 4);
    int* cnt = (int*)alloc((size_t)N * 4);
    float* dinv = (float*)alloc((size_t)N * 4);
    int* rowptr = (int*)alloc((size_t)(N + 1) * 4);
    int* cursor = (int*)alloc((size_t)N * 4);
    int2* csr = (int2*)alloc((size_t)E * 8);
    float* Wp = (float*)alloc((size_t)D * D * 4);
    float* cp = (float*)alloc((size_t)D * 4);
    int* bsum = (int*)alloc((size_t)gN * 4);

    k_init_cnt<<<gN, 256, 0, stream>>>(cnt, N);
    k_count<<<gE, 256, 0, stream>>>(dst, cnt, E);
    k_dinv<<<gN, 256, 0, stream>>>(cnt, dinv, N);
    k_blocksum<<<gN, 256, 0, stream>>>(cnt, bsum, N);
    k_scan_bsums<<<1, 1024, 0, stream>>>(bsum, gN, rowptr, N);
    k_local_scan<<<gN, 256, 0, stream>>>(cnt, bsum, rowptr, cursor, N);
    k_fill<<<gE, 256, 0, stream>>>(src, dst, dinv, cursor, csr, E);
    k_wprime<<<65, 256, 0, stream>>>(W2, M1, b2, c1, Wp, cp);

    // layer 0: t = S.x ; h0 = relu(t@W0+b0)
    k_agg<<<gAgg, 256, 0, stream>>>(x, rowptr, csr, dinv, bufA, N);
    k_gemm<0><<<gGemm, 256, 0, stream>>>(bufA, W0, b0, nullptr, nullptr, bufB, N);
    // layer 1
    k_agg<<<gAgg, 256, 0, stream>>>(bufB, rowptr, csr, dinv, bufA, N);
    k_gemm<0><<<gGemm, 256, 0, stream>>>(bufA, W1, b1, nullptr, nullptr, bufB, N);
    // layer 2 + fused MLP head
    k_agg<<<gAgg, 256, 0, stream>>>(bufB, rowptr, csr, dinv, bufA, N);
    k_gemm<1><<<gGemm, 256, 0, stream>>>(bufA, Wp, cp, m2, m2b, out, N);
}

// Round 3
// 300.941 us; speedup vs baseline: 1.3563x; 1.0864x over previous
//
#include <hip/hip_runtime.h>
#include <hip/hip_fp16.h>

constexpr int D = 128;

// ---------------- CSR build ----------------

__global__ void k_init_cnt(int* __restrict__ cnt, int n) {
    int i = blockIdx.x * 256 + threadIdx.x;
    if (i < n) cnt[i] = 0;
}

__global__ void k_count(const int* __restrict__ dst, int* __restrict__ cnt, int E) {
    int e = blockIdx.x * 256 + threadIdx.x;
    if (e < E) atomicAdd(&cnt[dst[e]], 1);
}

__global__ void k_dinv(const int* __restrict__ cnt, float* __restrict__ dinv, int n) {
    int i = blockIdx.x * 256 + threadIdx.x;
    if (i < n) dinv[i] = rsqrtf((float)(cnt[i] + 1));  // +1 self-loop
}

// --- 3-phase scan ---

__global__ __launch_bounds__(256) void k_blocksum(const int* __restrict__ cnt,
                                                  int* __restrict__ bsum, int n) {
    __shared__ int sm[256];
    int tid = threadIdx.x;
    int i = blockIdx.x * 256 + tid;
    sm[tid] = (i < n) ? cnt[i] : 0;
    __syncthreads();
    for (int off = 128; off > 0; off >>= 1) {
        if (tid < off) sm[tid] += sm[tid + off];
        __syncthreads();
    }
    if (tid == 0) bsum[blockIdx.x] = sm[0];
}

__global__ __launch_bounds__(1024) void k_scan_bsums(int* __restrict__ bsum, int nb,
                                                     int* __restrict__ rowptr, int n) {
    __shared__ int sm[1024];
    int tid = threadIdx.x;
    int v = (tid < nb) ? bsum[tid] : 0;
    sm[tid] = v;
    __syncthreads();
    for (int off = 1; off < 1024; off <<= 1) {
        int t = (tid >= off) ? sm[tid - off] : 0;
        __syncthreads();
        sm[tid] += t;
        __syncthreads();
    }
    if (tid < nb) bsum[tid] = sm[tid] - v;  // exclusive
    if (tid == 1023) rowptr[n] = sm[1023];
}

__global__ __launch_bounds__(256) void k_local_scan(const int* __restrict__ cnt,
                                                    const int* __restrict__ bsum,
                                                    int* __restrict__ rowptr,
                                                    int* __restrict__ cursor, int n) {
    __shared__ int sm[256];
    int tid = threadIdx.x;
    int i = blockIdx.x * 256 + tid;
    int v = (i < n) ? cnt[i] : 0;
    sm[tid] = v;
    __syncthreads();
    for (int off = 1; off < 256; off <<= 1) {
        int t = (tid >= off) ? sm[tid - off] : 0;
        __syncthreads();
        sm[tid] += t;
        __syncthreads();
    }
    if (i < n) {
        int rp = bsum[blockIdx.x] + sm[tid] - v;
        rowptr[i] = rp;
        cursor[i] = rp;
    }
}

__global__ void k_fill(const int* __restrict__ src, const int* __restrict__ dst,
                       const float* __restrict__ dinv, int* __restrict__ cursor,
                       int2* __restrict__ csr, int E) {
    int e = blockIdx.x * 256 + threadIdx.x;
    if (e < E) {
        int s = src[e], d = dst[e];
        int p = atomicAdd(&cursor[d], 1);
        float w = dinv[s] * dinv[d];
        csr[p] = make_int2(s, __float_as_int(w));
    }
}

// ---------------- fp32 -> fp16 conversion (4 elems/thread) ----------------

__global__ void k_cvt_h(const float* __restrict__ in, __half* __restrict__ outh, int n4) {
    int i = blockIdx.x * 256 + threadIdx.x;
    if (i < n4) {
        float4 v = reinterpret_cast<const float4*>(in)[i];
        __half ho[4] = {__float2half(v.x), __float2half(v.y), __float2half(v.z),
                        __float2half(v.w)};
        reinterpret_cast<uint2*>(outh)[i] = *reinterpret_cast<uint2*>(ho);
    }
}

// ---------------- W' = W2 @ M1 ; c' = b2 @ M1 + c1 ----------------

__global__ void k_wprime(const float* __restrict__ W2, const float* __restrict__ M1,
                         const float* __restrict__ b2, const float* __restrict__ c1,
                         float* __restrict__ Wp, float* __restrict__ cp) {
    int b = blockIdx.x, t = threadIdx.x;
    if (b < 64) {
        int idx = b * 256 + t;
        int i = idx >> 7, j = idx & 127;
        float acc = 0.f;
        for (int k = 0; k < 128; ++k) acc = fmaf(W2[i * 128 + k], M1[k * 128 + j], acc);
        Wp[idx] = acc;
    } else if (t < 128) {
        float acc = c1[t];
        for (int k = 0; k < 128; ++k) acc = fmaf(b2[k], M1[k * 128 + t], acc);
        cp[t] = acc;
    }
}

// ---------------- aggregation: out_fp32 = S . A_fp16 ----------------

__global__ __launch_bounds__(256) void k_agg_h(const uint* __restrict__ Ah,  // [n*64] packed half2
                                               const int* __restrict__ rowptr,
                                               const int2* __restrict__ csr,
                                               const float* __restrict__ dinv,
                                               float* __restrict__ out, int n) {
    int wave = threadIdx.x >> 6;
    int lane = threadIdx.x & 63;
    int i = blockIdx.x * 4 + wave;
    if (i >= n) return;
    float ws = dinv[i];
    ws = ws * ws;
    uint g = Ah[i * 64 + lane];
    float2 a = __half22float2(*reinterpret_cast<const __half2*>(&g));
    float accx = ws * a.x, accy = ws * a.y;
    int beg = rowptr[i], end = rowptr[i + 1];
    int e = beg;
    for (; e + 2 <= end; e += 2) {
        int2 p0 = csr[e];
        int2 p1 = csr[e + 1];
        uint g0 = Ah[p0.x * 64 + lane];
        uint g1 = Ah[p1.x * 64 + lane];
        float2 v0 = __half22float2(*reinterpret_cast<const __half2*>(&g0));
        float2 v1 = __half22float2(*reinterpret_cast<const __half2*>(&g1));
        float w0 = __int_as_float(p0.y);
        float w1 = __int_as_float(p1.y);
        accx = fmaf(w0, v0.x, accx);
        accy = fmaf(w0, v0.y, accy);
        accx = fmaf(w1, v1.x, accx);
        accy = fmaf(w1, v1.y, accy);
    }
    if (e < end) {
        int2 p0 = csr[e];
        uint g0 = Ah[p0.x * 64 + lane];
        float2 v0 = __half22float2(*reinterpret_cast<const __half2*>(&g0));
        float w0 = __int_as_float(p0.y);
        accx = fmaf(w0, v0.x, accx);
        accy = fmaf(w0, v0.y, accy);
    }
    float2 o;
    o.x = accx;
    o.y = accy;
    reinterpret_cast<float2*>(out)[i * 64 + lane] = o;
}

// ---------------- GEMM: out = epilogue(A @ W + bias) ----------------
// MODE 0: out[N,128] = fp16( relu(A@W + bias) )
// MODE 1: out[N,1]   = relu(A@W + bias) . m2 + m2b[0]   (fp32)

template <int MODE>
__global__ __launch_bounds__(256) void k_gemm(const float* __restrict__ A,
                                              const float* __restrict__ W,
                                              const float* __restrict__ bias,
                                              const float* __restrict__ m2,
                                              const float* __restrict__ m2b,
                                              void* __restrict__ outv, int n) {
    __shared__ float Ht[16 * 64];    // k-major: Ht[k][row]
    __shared__ float Wt[16 * 128];   // Wt[k][col]
    int tid = threadIdx.x;
    int rg = tid >> 4;   // 0..15 -> rows rg*4 .. rg*4+3
    int cg = tid & 15;   // 0..15 -> cols cg*8 .. cg*8+7
    int r0 = blockIdx.x * 64;

    float acc[4][8];
#pragma unroll
    for (int ri = 0; ri < 4; ++ri)
#pragma unroll
        for (int ci = 0; ci < 8; ++ci) acc[ri][ci] = 0.f;

    for (int k0 = 0; k0 < 128; k0 += 16) {
        {
            int row = tid >> 2;  // 0..63
            int kq = tid & 3;    // 0..3
            int grow = r0 + row;
            if (grow > n - 1) grow = n - 1;
            float4 v = *reinterpret_cast<const float4*>(&A[grow * 128 + k0 + kq * 4]);
            Ht[(kq * 4 + 0) * 64 + row] = v.x;
            Ht[(kq * 4 + 1) * 64 + row] = v.y;
            Ht[(kq * 4 + 2) * 64 + row] = v.z;
            Ht[(kq * 4 + 3) * 64 + row] = v.w;
        }
        for (int q = tid; q < 512; q += 256) {
            int kk = q >> 5;
            int cc = (q & 31) * 4;
            *reinterpret_cast<float4*>(&Wt[kk * 128 + cc]) =
                *reinterpret_cast<const float4*>(&W[(k0 + kk) * 128 + cc]);
        }
        __syncthreads();
#pragma unroll
        for (int k = 0; k < 16; ++k) {
            float4 a = *reinterpret_cast<float4*>(&Ht[k * 64 + rg * 4]);
            float4 b0 = *reinterpret_cast<float4*>(&Wt[k * 128 + cg * 8]);
            float4 b1 = *reinterpret_cast<float4*>(&Wt[k * 128 + cg * 8 + 4]);
            float av[4] = {a.x, a.y, a.z, a.w};
            float bv[8] = {b0.x, b0.y, b0.z, b0.w, b1.x, b1.y, b1.z, b1.w};
#pragma unroll
            for (int ri = 0; ri < 4; ++ri)
#pragma unroll
                for (int ci = 0; ci < 8; ++ci)
                    acc[ri][ci] = fmaf(av[ri], bv[ci], acc[ri][ci]);
        }
        __syncthreads();
    }

    float4 bb0 = *reinterpret_cast<const float4*>(&bias[cg * 8]);
    float4 bb1 = *reinterpret_cast<const float4*>(&bias[cg * 8 + 4]);
    float bv[8] = {bb0.x, bb0.y, bb0.z, bb0.w, bb1.x, bb1.y, bb1.z, bb1.w};

    if (MODE == 0) {
        __half* outh = (__half*)outv;
#pragma unroll
        for (int ri = 0; ri < 4; ++ri) {
            int r = r0 + rg * 4 + ri;
            if (r < n) {
                __half ho[8];
#pragma unroll
                for (int ci = 0; ci < 8; ++ci)
                    ho[ci] = __float2half(fmaxf(acc[ri][ci] + bv[ci], 0.f));
                *reinterpret_cast<uint4*>(&outh[r * 128 + cg * 8]) =
                    *reinterpret_cast<const uint4*>(ho);
            }
        }
    } else {
        float* out = (float*)outv;
        float4 mm0 = *reinterpret_cast<const float4*>(&m2[cg * 8]);
        float4 mm1 = *reinterpret_cast<const float4*>(&m2[cg * 8 + 4]);
        float mv[8] = {mm0.x, mm0.y, mm0.z, mm0.w, mm1.x, mm1.y, mm1.z, mm1.w};
        float m2bv = m2b[0];
#pragma unroll
        for (int ri = 0; ri < 4; ++ri) {
            float p = 0.f;
#pragma unroll
            for (int ci = 0; ci < 8; ++ci) {
                float v = fmaxf(acc[ri][ci] + bv[ci], 0.f);
                p = fmaf(v, mv[ci], p);
            }
            p += __shfl_xor(p, 1);
            p += __shfl_xor(p, 2);
            p += __shfl_xor(p, 4);
            p += __shfl_xor(p, 8);
            int r = r0 + rg * 4 + ri;
            if (cg == 0 && r < n) out[r] = p + m2bv;
        }
    }
}

// ---------------- launch ----------------

extern "C" void kernel_launch(void* const* d_in, const int* in_sizes, int n_in,
                              void* d_out, int out_size, void* d_ws, size_t ws_size,
                              hipStream_t stream) {
    const float* x = (const float*)d_in[0];
    const int* ei = (const int*)d_in[1];
    const float* W0 = (const float*)d_in[2];
    const float* b0 = (const float*)d_in[3];
    const float* W1 = (const float*)d_in[4];
    const float* b1 = (const float*)d_in[5];
    const float* W2 = (const float*)d_in[6];
    const float* b2 = (const float*)d_in[7];
    const float* M1 = (const float*)d_in[8];
    const float* c1 = (const float*)d_in[9];
    const float* m2 = (const float*)d_in[10];
    const float* m2b = (const float*)d_in[11];
    float* out = (float*)d_out;

    int N = in_sizes[0] / D;
    int E = in_sizes[1] / 2;
    const int* src = ei;
    const int* dst = ei + E;

    char* ws = (char*)d_ws;
    size_t off = 0;
    auto alloc = [&](size_t bytes) -> void* {
        void* p = ws + off;
        off += (bytes + 255) & ~(size_t)255;
        return p;
    };

    int gN = (N + 255) / 256;
    int gE = (E + 255) / 256;
    int gAgg = (N + 3) / 4;
    int gGemm = (N + 63) / 64;
    int nElem4 = N * D / 4;
    int gCvt = (nElem4 + 255) / 256;

    float* bufT = (float*)alloc((size_t)N * D * 4);      // agg out / gemm in (fp32)
    __half* bufH = (__half*)alloc((size_t)N * D * 2);    // gemm out / agg in (fp16)
    __half* xh = (__half*)alloc((size_t)N * D * 2);      // fp16 copy of x
    int* cnt = (int*)alloc((size_t)N * 4);
    float* dinv = (float*)alloc((size_t)N * 4);
    int* rowptr = (int*)alloc((size_t)(N + 1) * 4);
    int* cursor = (int*)alloc((size_t)N * 4);
    int2* csr = (int2*)alloc((size_t)E * 8);
    float* Wp = (float*)alloc((size_t)D * D * 4);
    float* cp = (float*)alloc((size_t)D * 4);
    int* bsum = (int*)alloc((size_t)gN * 4);

    k_cvt_h<<<gCvt, 256, 0, stream>>>(x, xh, nElem4);
    k_init_cnt<<<gN, 256, 0, stream>>>(cnt, N);
    k_count<<<gE, 256, 0, stream>>>(dst, cnt, E);
    k_dinv<<<gN, 256, 0, stream>>>(cnt, dinv, N);
    k_blocksum<<<gN, 256, 0, stream>>>(cnt, bsum, N);
    k_scan_bsums<<<1, 1024, 0, stream>>>(bsum, gN, rowptr, N);
    k_local_scan<<<gN, 256, 0, stream>>>(cnt, bsum, rowptr, cursor, N);
    k_fill<<<gE, 256, 0, stream>>>(src, dst, dinv, cursor, csr, E);
    k_wprime<<<65, 256, 0, stream>>>(W2, M1, b2, c1, Wp, cp);

    // layer 0: t = S.xh ; h0 = fp16(relu(t@W0+b0))
    k_agg_h<<<gAgg, 256, 0, stream>>>((const uint*)xh, rowptr, csr, dinv, bufT, N);
    k_gemm<0><<<gGemm, 256, 0, stream>>>(bufT, W0, b0, nullptr, nullptr, bufH, N);
    // layer 1
    k_agg_h<<<gAgg, 256, 0, stream>>>((const uint*)bufH, rowptr, csr, dinv, bufT, N);
    k_gemm<0><<<gGemm, 256, 0, stream>>>(bufT, W1, b1, nullptr, nullptr, bufH, N);
    // layer 2 + fused MLP head
    k_agg_h<<<gAgg, 256, 0, stream>>>((const uint*)bufH, rowptr, csr, dinv, bufT, N);
    k_gemm<1><<<gGemm, 256, 0, stream>>>(bufT, Wp, cp, m2, m2b, out, N);
}

// Round 4
// 275.061 us; speedup vs baseline: 1.4839x; 1.0941x over previous
//
#include <hip/hip_runtime.h>
#include <hip/hip_fp16.h>

constexpr int D = 128;

// ---------------- CSR build ----------------

__global__ void k_count(const int* __restrict__ dst, int* __restrict__ cnt, int E) {
    int e = blockIdx.x * 256 + threadIdx.x;
    if (e < E) atomicAdd(&cnt[dst[e]], 1);
}

// dinv + per-block sum in one pass over cnt
__global__ __launch_bounds__(256) void k_deg_stats(const int* __restrict__ cnt,
                                                   float* __restrict__ dinv,
                                                   int* __restrict__ bsum, int n) {
    __shared__ int sm[256];
    int tid = threadIdx.x;
    int i = blockIdx.x * 256 + tid;
    int c = (i < n) ? cnt[i] : 0;
    if (i < n) dinv[i] = rsqrtf((float)(c + 1));  // +1 self-loop
    sm[tid] = c;
    __syncthreads();
    for (int off = 128; off > 0; off >>= 1) {
        if (tid < off) sm[tid] += sm[tid + off];
        __syncthreads();
    }
    if (tid == 0) bsum[blockIdx.x] = sm[0];
}

__global__ __launch_bounds__(1024) void k_scan_bsums(int* __restrict__ bsum, int nb,
                                                     int* __restrict__ rowptr, int n) {
    __shared__ int sm[1024];
    int tid = threadIdx.x;
    int v = (tid < nb) ? bsum[tid] : 0;
    sm[tid] = v;
    __syncthreads();
    for (int off = 1; off < 1024; off <<= 1) {
        int t = (tid >= off) ? sm[tid - off] : 0;
        __syncthreads();
        sm[tid] += t;
        __syncthreads();
    }
    if (tid < nb) bsum[tid] = sm[tid] - v;  // exclusive
    if (tid == 1023) rowptr[n] = sm[1023];
}

__global__ __launch_bounds__(256) void k_local_scan(const int* __restrict__ cnt,
                                                    const int* __restrict__ bsum,
                                                    int* __restrict__ rowptr,
                                                    int* __restrict__ cursor, int n) {
    __shared__ int sm[256];
    int tid = threadIdx.x;
    int i = blockIdx.x * 256 + tid;
    int v = (i < n) ? cnt[i] : 0;
    sm[tid] = v;
    __syncthreads();
    for (int off = 1; off < 256; off <<= 1) {
        int t = (tid >= off) ? sm[tid - off] : 0;
        __syncthreads();
        sm[tid] += t;
        __syncthreads();
    }
    if (i < n) {
        int rp = bsum[blockIdx.x] + sm[tid] - v;
        rowptr[i] = rp;
        cursor[i] = rp;
    }
}

template <typename IdxT>
__global__ void k_fill(const int* __restrict__ src, const int* __restrict__ dst,
                       int* __restrict__ cursor, IdxT* __restrict__ csr, int E) {
    int e = blockIdx.x * 256 + threadIdx.x;
    if (e < E) {
        int s = src[e], d = dst[e];
        int p = atomicAdd(&cursor[d], 1);
        csr[p] = (IdxT)s;
    }
}

// ---------------- fp32 -> fp16 with dinv pre-scale ----------------

__global__ void k_cvt_h(const float* __restrict__ in, const float* __restrict__ dinv,
                        __half* __restrict__ outh, int n4) {
    int i = blockIdx.x * 256 + threadIdx.x;
    if (i < n4) {
        float4 v = reinterpret_cast<const float4*>(in)[i];
        float dd = dinv[i >> 5];  // 32 float4 per row of 128
        __half ho[4] = {__float2half(v.x * dd), __float2half(v.y * dd),
                        __float2half(v.z * dd), __float2half(v.w * dd)};
        reinterpret_cast<uint2*>(outh)[i] = *reinterpret_cast<uint2*>(ho);
    }
}

// ---------------- W' = W2 @ M1 ; c' = b2 @ M1 + c1 ----------------

__global__ void k_wprime(const float* __restrict__ W2, const float* __restrict__ M1,
                         const float* __restrict__ b2, const float* __restrict__ c1,
                         float* __restrict__ Wp, float* __restrict__ cp) {
    int b = blockIdx.x, t = threadIdx.x;
    if (b < 64) {
        int idx = b * 256 + t;
        int i = idx >> 7, j = idx & 127;
        float acc = 0.f;
        for (int k = 0; k < 128; ++k) acc = fmaf(W2[i * 128 + k], M1[k * 128 + j], acc);
        Wp[idx] = acc;
    } else if (t < 128) {
        float acc = c1[t];
        for (int k = 0; k < 128; ++k) acc = fmaf(b2[k], M1[k * 128 + t], acc);
        cp[t] = acc;
    }
}

// ---------------- aggregation: t_i = dinv_i * (sum_{j->i} g_j + g_i), g fp16 ----------------

template <typename IdxT>
__global__ __launch_bounds__(256) void k_agg_h(const uint* __restrict__ Ah,  // packed half2 [n*64]
                                               const int* __restrict__ rowptr,
                                               const IdxT* __restrict__ csr,
                                               const float* __restrict__ dinv,
                                               float* __restrict__ out, int n) {
    int wave = threadIdx.x >> 6;
    int lane = threadIdx.x & 63;
    int i = blockIdx.x * 4 + wave;
    if (i >= n) return;
    float di = dinv[i];
    uint g = Ah[i * 64 + lane];
    float2 a = __half22float2(*reinterpret_cast<const __half2*>(&g));
    float accx = a.x, accy = a.y;  // self term g_i
    int beg = rowptr[i], end = rowptr[i + 1];
    int e = beg;
    for (; e + 4 <= end; e += 4) {
        int s0 = (int)csr[e];
        int s1 = (int)csr[e + 1];
        int s2 = (int)csr[e + 2];
        int s3 = (int)csr[e + 3];
        uint g0 = Ah[s0 * 64 + lane];
        uint g1 = Ah[s1 * 64 + lane];
        uint g2 = Ah[s2 * 64 + lane];
        uint g3 = Ah[s3 * 64 + lane];
        float2 v0 = __half22float2(*reinterpret_cast<const __half2*>(&g0));
        float2 v1 = __half22float2(*reinterpret_cast<const __half2*>(&g1));
        float2 v2 = __half22float2(*reinterpret_cast<const __half2*>(&g2));
        float2 v3 = __half22float2(*reinterpret_cast<const __half2*>(&g3));
        accx += v0.x + v1.x;
        accy += v0.y + v1.y;
        accx += v2.x + v3.x;
        accy += v2.y + v3.y;
    }
    for (; e < end; ++e) {
        int s0 = (int)csr[e];
        uint g0 = Ah[s0 * 64 + lane];
        float2 v0 = __half22float2(*reinterpret_cast<const __half2*>(&g0));
        accx += v0.x;
        accy += v0.y;
    }
    float2 o;
    o.x = di * accx;
    o.y = di * accy;
    reinterpret_cast<float2*>(out)[i * 64 + lane] = o;
}

// ---------------- GEMM: out = epilogue(A @ W + bias) ----------------
// MODE 0: out[N,128] = fp16( dinv[r] * relu(A@W + bias) )   (pre-scaled for next agg)
// MODE 1: out[N,1]   = relu(A@W + bias) . m2 + m2b[0]       (fp32)

template <int MODE>
__global__ __launch_bounds__(256) void k_gemm(const float* __restrict__ A,
                                              const float* __restrict__ W,
                                              const float* __restrict__ bias,
                                              const float* __restrict__ dinv,
                                              const float* __restrict__ m2,
                                              const float* __restrict__ m2b,
                                              void* __restrict__ outv, int n) {
    __shared__ float Ht[16 * 64];    // k-major: Ht[k][row]
    __shared__ float Wt[16 * 128];   // Wt[k][col]
    int tid = threadIdx.x;
    int rg = tid >> 4;   // rows rg*4 .. rg*4+3
    int cg = tid & 15;   // cols cg*8 .. cg*8+7
    int r0 = blockIdx.x * 64;

    float acc[4][8];
#pragma unroll
    for (int ri = 0; ri < 4; ++ri)
#pragma unroll
        for (int ci = 0; ci < 8; ++ci) acc[ri][ci] = 0.f;

    for (int k0 = 0; k0 < 128; k0 += 16) {
        {
            int row = tid >> 2;
            int kq = tid & 3;
            int grow = r0 + row;
            if (grow > n - 1) grow = n - 1;
            float4 v = *reinterpret_cast<const float4*>(&A[grow * 128 + k0 + kq * 4]);
            Ht[(kq * 4 + 0) * 64 + row] = v.x;
            Ht[(kq * 4 + 1) * 64 + row] = v.y;
            Ht[(kq * 4 + 2) * 64 + row] = v.z;
            Ht[(kq * 4 + 3) * 64 + row] = v.w;
        }
        for (int q = tid; q < 512; q += 256) {
            int kk = q >> 5;
            int cc = (q & 31) * 4;
            *reinterpret_cast<float4*>(&Wt[kk * 128 + cc]) =
                *reinterpret_cast<const float4*>(&W[(k0 + kk) * 128 + cc]);
        }
        __syncthreads();
#pragma unroll
        for (int k = 0; k < 16; ++k) {
            float4 a = *reinterpret_cast<float4*>(&Ht[k * 64 + rg * 4]);
            float4 b0 = *reinterpret_cast<float4*>(&Wt[k * 128 + cg * 8]);
            float4 b1 = *reinterpret_cast<float4*>(&Wt[k * 128 + cg * 8 + 4]);
            float av[4] = {a.x, a.y, a.z, a.w};
            float bv[8] = {b0.x, b0.y, b0.z, b0.w, b1.x, b1.y, b1.z, b1.w};
#pragma unroll
            for (int ri = 0; ri < 4; ++ri)
#pragma unroll
                for (int ci = 0; ci < 8; ++ci)
                    acc[ri][ci] = fmaf(av[ri], bv[ci], acc[ri][ci]);
        }
        __syncthreads();
    }

    float4 bb0 = *reinterpret_cast<const float4*>(&bias[cg * 8]);
    float4 bb1 = *reinterpret_cast<const float4*>(&bias[cg * 8 + 4]);
    float bv[8] = {bb0.x, bb0.y, bb0.z, bb0.w, bb1.x, bb1.y, bb1.z, bb1.w};

    if (MODE == 0) {
        __half* outh = (__half*)outv;
#pragma unroll
        for (int ri = 0; ri < 4; ++ri) {
            int r = r0 + rg * 4 + ri;
            if (r < n) {
                float dr = dinv[r];
                __half ho[8];
#pragma unroll
                for (int ci = 0; ci < 8; ++ci)
                    ho[ci] = __float2half(dr * fmaxf(acc[ri][ci] + bv[ci], 0.f));
                *reinterpret_cast<uint4*>(&outh[r * 128 + cg * 8]) =
                    *reinterpret_cast<const uint4*>(ho);
            }
        }
    } else {
        float* out = (float*)outv;
        float4 mm0 = *reinterpret_cast<const float4*>(&m2[cg * 8]);
        float4 mm1 = *reinterpret_cast<const float4*>(&m2[cg * 8 + 4]);
        float mv[8] = {mm0.x, mm0.y, mm0.z, mm0.w, mm1.x, mm1.y, mm1.z, mm1.w};
        float m2bv = m2b[0];
#pragma unroll
        for (int ri = 0; ri < 4; ++ri) {
            float p = 0.f;
#pragma unroll
            for (int ci = 0; ci < 8; ++ci) {
                float v = fmaxf(acc[ri][ci] + bv[ci], 0.f);
                p = fmaf(v, mv[ci], p);
            }
            p += __shfl_xor(p, 1);
            p += __shfl_xor(p, 2);
            p += __shfl_xor(p, 4);
            p += __shfl_xor(p, 8);
            int r = r0 + rg * 4 + ri;
            if (cg == 0 && r < n) out[r] = p + m2bv;
        }
    }
}

// ---------------- launch ----------------

extern "C" void kernel_launch(void* const* d_in, const int* in_sizes, int n_in,
                              void* d_out, int out_size, void* d_ws, size_t ws_size,
                              hipStream_t stream) {
    const float* x = (const float*)d_in[0];
    const int* ei = (const int*)d_in[1];
    const float* W0 = (const float*)d_in[2];
    const float* b0 = (const float*)d_in[3];
    const float* W1 = (const float*)d_in[4];
    const float* b1 = (const float*)d_in[5];
    const float* W2 = (const float*)d_in[6];
    const float* b2 = (const float*)d_in[7];
    const float* M1 = (const float*)d_in[8];
    const float* c1 = (const float*)d_in[9];
    const float* m2 = (const float*)d_in[10];
    const float* m2b = (const float*)d_in[11];
    float* out = (float*)d_out;

    int N = in_sizes[0] / D;
    int E = in_sizes[1] / 2;
    const int* src = ei;
    const int* dst = ei + E;

    char* ws = (char*)d_ws;
    size_t off = 0;
    auto alloc = [&](size_t bytes) -> void* {
        void* p = ws + off;
        off += (bytes + 255) & ~(size_t)255;
        return p;
    };

    int gN = (N + 255) / 256;
    int gE = (E + 255) / 256;
    int gAgg = (N + 3) / 4;
    int gGemm = (N + 63) / 64;
    int nElem4 = N * D / 4;
    int gCvt = (nElem4 + 255) / 256;

    float* bufT = (float*)alloc((size_t)N * D * 4);      // agg out / gemm in (fp32)
    __half* bufH = (__half*)alloc((size_t)N * D * 2);    // gemm out / agg in (fp16, dinv-scaled)
    __half* xh = (__half*)alloc((size_t)N * D * 2);      // fp16 dinv-scaled x
    int* cnt = (int*)alloc((size_t)N * 4);
    float* dinv = (float*)alloc((size_t)N * 4);
    int* rowptr = (int*)alloc((size_t)(N + 1) * 4);
    int* cursor = (int*)alloc((size_t)N * 4);
    void* csr = alloc((size_t)E * 4);  // ushort (E*2) or uint (E*4)
    float* Wp = (float*)alloc((size_t)D * D * 4);
    float* cp = (float*)alloc((size_t)D * 4);
    int* bsum = (int*)alloc((size_t)gN * 4);

    bool small_idx = (N <= 65535);

    hipMemsetAsync(cnt, 0, (size_t)N * 4, stream);
    k_count<<<gE, 256, 0, stream>>>(dst, cnt, E);
    k_deg_stats<<<gN, 256, 0, stream>>>(cnt, dinv, bsum, N);
    k_scan_bsums<<<1, 1024, 0, stream>>>(bsum, gN, rowptr, N);
    k_local_scan<<<gN, 256, 0, stream>>>(cnt, bsum, rowptr, cursor, N);
    if (small_idx)
        k_fill<ushort><<<gE, 256, 0, stream>>>(src, dst, cursor, (ushort*)csr, E);
    else
        k_fill<uint><<<gE, 256, 0, stream>>>(src, dst, cursor, (uint*)csr, E);
    k_cvt_h<<<gCvt, 256, 0, stream>>>(x, dinv, xh, nElem4);
    k_wprime<<<65, 256, 0, stream>>>(W2, M1, b2, c1, Wp, cp);

    auto agg = [&](const __half* in_h, float* out_t) {
        if (small_idx)
            k_agg_h<ushort><<<gAgg, 256, 0, stream>>>((const uint*)in_h, rowptr,
                                                      (const ushort*)csr, dinv, out_t, N);
        else
            k_agg_h<uint><<<gAgg, 256, 0, stream>>>((const uint*)in_h, rowptr,
                                                    (const uint*)csr, dinv, out_t, N);
    };

    // layer 0
    agg(xh, bufT);
    k_gemm<0><<<gGemm, 256, 0, stream>>>(bufT, W0, b0, dinv, nullptr, nullptr, bufH, N);
    // layer 1
    agg(bufH, bufT);
    k_gemm<0><<<gGemm, 256, 0, stream>>>(bufT, W1, b1, dinv, nullptr, nullptr, bufH, N);
    // layer 2 + fused MLP head
    agg(bufH, bufT);
    k_gemm<1><<<gGemm, 256, 0, stream>>>(bufT, Wp, cp, dinv, m2, m2b, out, N);
}